// Round 9
// baseline (681.619 us; speedup 1.0000x reference)
//
#include <hip/hip_runtime.h>
#include <math.h>
#include <limits.h>

#define BB 1024
#define SS 256
#define DD 64
#define NI 4
#define NG 8
#define TE_N 100
#define PMAX 57420
#define ROWP 100            // table row stride (400B, float4-aligned)
#define TPB 16              // positions per k_tables block
#define SWP 260             // swL row pad (bank-spread)

typedef _Float16 half8 __attribute__((ext_vector_type(8)));
typedef _Float16 half4 __attribute__((ext_vector_type(4)));
typedef float f32x4 __attribute__((ext_vector_type(4)));

// ws layout (float units) — fixed region first, hat chunk buffer last
#define OFF_FTH   ((size_t)0)
#define OFF_FDF   ((size_t)PMAX*ROWP)                 //  5,742,000
#define OFF_GTB   ((size_t)2*PMAX*ROWP)               // 11,484,000
#define OFF_FAC   (OFF_GTB + (size_t)BB*ROWP)         // 11,586,400
#define OFF_SCAL  (OFF_FAC + (size_t)BB*SS)           // 11,848,544
#define OFF_HAT   (OFF_SCAL + 32)                     // 11,848,576

__global__ void k_init(float* ws){
    if (threadIdx.x == 0){
        int* mi = (int*)(ws + OFF_SCAL);
        mi[0] = INT_MAX; mi[1] = INT_MAX; mi[2] = INT_MAX;
        ws[OFF_SCAL + 4] = 0.0f;
    }
}

__global__ void k_min(const float* __restrict__ tb, const float* __restrict__ th, float* ws){
    int gid = blockIdx.x * blockDim.x + threadIdx.x;
    int stride = gridDim.x * blockDim.x;
    int m0 = INT_MAX, m1 = INT_MAX, m2 = INT_MAX;
    for (int i = gid; i < BB*SS; i += stride){
        float t  = th[i];
        float t2 = tb[i >> 8];
        int i1 = (int)(t / 10000.0f);
        int i2 = (int)((t2 - t) / 10000.0f);
        m1 = min(m1, i1);
        m2 = min(m2, i2);
    }
    if (gid < BB) m0 = (int)(tb[gid] / 10000.0f);
    #pragma unroll
    for (int off = 1; off < 64; off <<= 1){
        m0 = min(m0, __shfl_xor(m0, off));
        m1 = min(m1, __shfl_xor(m1, off));
        m2 = min(m2, __shfl_xor(m2, off));
    }
    if ((threadIdx.x & 63) == 0){
        int* mi = (int*)(ws + OFF_SCAL);
        atomicMin(mi + 0, m0);
        atomicMin(mi + 1, m1);
        atomicMin(mi + 2, m2);
    }
}

// f_th[p,j] = TE(p) . W1[100:200, j] ; f_diff[p,j] = TE(p) . W1[200:300, j]
__global__ void k_tables(const float* __restrict__ W1, float* ws){
    int pbase = blockIdx.x * TPB;
    int t = threadIdx.x;                  // 128
    __shared__ float te[TPB][TE_N];
    for (int idx = t; idx < TPB*50; idx += 128){
        int pp = idx / 50, h = idx - pp*50;
        double div = exp((double)h * -0.09210340371976184); // -ln(10000)/100
        double a = (double)(pbase + pp) * div;
        te[pp][2*h]   = (float)sin(a);
        te[pp][2*h+1] = (float)cos(a);
    }
    __syncthreads();
    if (t < TE_N){
        float a1[TPB], a2[TPB];
        #pragma unroll
        for (int pp = 0; pp < TPB; pp++){ a1[pp] = 0.f; a2[pp] = 0.f; }
        for (int i = 0; i < TE_N; i++){
            float w1v = W1[(100+i)*100 + t];
            float w2v = W1[(200+i)*100 + t];
            #pragma unroll
            for (int pp = 0; pp < TPB; pp++){
                float v = te[pp][i];
                a1[pp] += v * w1v;
                a2[pp] += v * w2v;
            }
        }
        for (int pp = 0; pp < TPB; pp++){
            int p = pbase + pp;
            if (p < PMAX){
                ws[OFF_FTH + (size_t)p*ROWP + t] = a1[pp];
                ws[OFF_FDF + (size_t)p*ROWP + t] = a2[pp];
            }
        }
    }
}

// g_tb[b,j] = TE(pos_tb(b)) . W1[0:100, j] + b1[j]
__global__ void k_gtb(const float* __restrict__ tb, const float* __restrict__ W1,
                      const float* __restrict__ b1, float* ws){
    int b = blockIdx.x;
    int t = threadIdx.x;
    const int* mi = (const int*)(ws + OFF_SCAL);
    int p = (int)(tb[b] / 10000.0f) - mi[0];
    __shared__ float te[TE_N];
    if (t < TE_N/2){
        double div = exp((double)t * -0.09210340371976184);
        double a = (double)p * div;
        te[2*t]   = (float)sin(a);
        te[2*t+1] = (float)cos(a);
    }
    __syncthreads();
    if (t < TE_N){
        float a1 = b1[t];
        for (int i = 0; i < TE_N; i++) a1 += te[i] * W1[i*100 + t];
        ws[OFF_GTB + (size_t)b*ROWP + t] = a1;
    }
}

// tf[b,s] = sigmoid(MLP) — wave per (b,s) pair, coalesced row gathers.
__global__ void __launch_bounds__(256) k_factor(const float* __restrict__ tbatch,
                         const float* __restrict__ th_, const float* __restrict__ W2,
                         const float* __restrict__ b2, float* ws){
    int b  = blockIdx.x >> 1;
    int sh = blockIdx.x & 1;
    int t  = threadIdx.x;
    int lane = t & 63, wv = t >> 6;
    __shared__ float sgtb[TE_N];
    if (t < TE_N) sgtb[t] = ws[OFF_GTB + (size_t)b*ROWP + t];
    __syncthreads();

    bool tail = (lane < 36);
    float w2a = W2[lane];
    float w2b = tail ? W2[64 + lane] : 0.f;
    float ga  = sgtb[lane];
    float gb  = tail ? sgtb[64 + lane] : 0.f;
    float bias = b2[0];

    int sbase = sh*128 + wv*32;
    const int* mi = (const int*)(ws + OFF_SCAL);
    int pth = 0, pdf = 0;
    if (lane < 32){
        float thv = th_[(size_t)b*SS + sbase + lane];
        float tbv = tbatch[b];
        pth = (int)(thv / 10000.0f) - mi[1];
        pdf = (int)((tbv - thv) / 10000.0f) - mi[2];
        pth = min(max(pth, 0), PMAX-1);
        pdf = min(max(pdf, 0), PMAX-1);
    }

    float tfkeep = 0.f;
    float r1acc  = 0.f;
    #pragma unroll 4
    for (int i = 0; i < 32; i++){
        int p1 = __shfl(pth, i);
        int p2 = __shfl(pdf, i);
        const float* r1 = ws + OFF_FTH + (size_t)p1*ROWP;
        const float* r2 = ws + OFF_FDF + (size_t)p2*ROWP;
        float a  = r1[lane];
        float c  = r2[lane];
        float a2 = tail ? r1[64 + lane] : 0.f;
        float c2 = tail ? r2[64 + lane] : 0.f;
        float h = fmaxf(ga + a + c, 0.f) * w2a;
        if (tail) h += fmaxf(gb + a2 + c2, 0.f) * w2b;
        #pragma unroll
        for (int off = 1; off < 64; off <<= 1) h += __shfl_xor(h, off);
        float tf = 1.f / (1.f + expf(-(h + bias)));
        if (lane == i){ tfkeep = tf; r1acc += tf*tf; }
    }
    if (lane < 32) ws[OFF_FAC + (size_t)b*SS + sbase + lane] = tfkeep;
    #pragma unroll
    for (int off = 1; off < 64; off <<= 1) r1acc += __shfl_xor(r1acc, off);
    if (lane == 0) atomicAdd(ws + OFF_SCAL + 4, r1acc);
}

// gate factor: ws[OFF_FAC + b*SS + s] += sum_g softmax_g(X.gate_emb) * gate(th)
__global__ void __launch_bounds__(256) k_gate(const float* __restrict__ X,
      const float* __restrict__ th_, const float* __restrict__ phase,
      const float* __restrict__ tao, const float* __restrict__ ratio,
      const float* __restrict__ ge, float* ws){
    __shared__ float sge[NG][DD];
    int t = threadIdx.x;
    for (int i = t; i < DD*NG; i += 256) sge[i & 7][i >> 3] = ge[i];
    __syncthreads();
    int gid = blockIdx.x * 256 + t;

    float lg[NG];
    #pragma unroll
    for (int g = 0; g < NG; g++) lg[g] = 0.f;
    const float4* xr = (const float4*)(X + (size_t)gid*DD);
    #pragma unroll 4
    for (int dc = 0; dc < 16; dc++){
        float4 xv = xr[dc];
        #pragma unroll
        for (int g = 0; g < NG; g++){
            lg[g] += xv.x*sge[g][dc*4+0] + xv.y*sge[g][dc*4+1]
                   + xv.z*sge[g][dc*4+2] + xv.w*sge[g][dc*4+3];
        }
    }
    float mx = lg[0];
    #pragma unroll
    for (int g = 1; g < NG; g++) mx = fmaxf(mx, lg[g]);
    float thv = th_[gid];
    float es = 0.f, gf = 0.f;
    #pragma unroll
    for (int g = 0; g < NG; g++){
        float e = expf(lg[g] - mx);
        es += e;
        float phv = fmodf(thv - phase[g], tao[g]) / tao[g];
        float gv = (phv < ratio[g]) ? fmaxf(sinf(3.14159f*phv/ratio[g]), 0.f) : 0.1f*phv;
        gf += e * gv;
    }
    ws[OFF_FAC + gid] += gf / es;
}

// hat[bl,s,kd] = sum_j Wb[s,kd,j] * X[b0+bl,s,j]  — split-fp16 MFMA.
__global__ void __launch_bounds__(512, 2)
k_hat(const float* __restrict__ X, const float* __restrict__ Wb,
      float* __restrict__ hat, int b0, int nb){
    int btile = blockIdx.x;      // 64-row b tile
    int s     = blockIdx.y;
    int t     = threadIdx.x;     // 512
    int rows = nb - btile*64; if (rows > 64) rows = 64;

    __shared__ _Float16 lds[40960];   // 80 KB

    const float* xbase = X + ((size_t)(b0 + btile*64)*SS + s)*DD;
    #pragma unroll
    for (int i = 0; i < 2; i++){
        int q = t + 512*i;
        int r = q >> 4, jf = q & 15;
        float4 v;
        if (r < rows) v = *(const float4*)(xbase + (size_t)r*SS*DD + jf*4);
        else { v.x = 0.f; v.y = 0.f; v.z = 0.f; v.w = 0.f; }
        half4 h, l;
        h.x = (_Float16)v.x; h.y = (_Float16)v.y; h.z = (_Float16)v.z; h.w = (_Float16)v.w;
        l.x = (_Float16)(v.x - (float)h.x); l.y = (_Float16)(v.y - (float)h.y);
        l.z = (_Float16)(v.z - (float)h.z); l.w = (_Float16)(v.w - (float)h.w);
        int bt = r >> 4, rowin = r & 15;
        int j0 = jf*4;
        int kk = j0 >> 5, jb = (j0 & 31) >> 3, e0 = j0 & 7;
        int lane = rowin + 16*jb;
        int base = ((bt*2 + kk)*2)*512 + lane*8 + e0;
        *(half4*)(lds + base)       = h;
        *(half4*)(lds + base + 512) = l;
    }
    const float* wbase = Wb + (size_t)s*16384;
    #pragma unroll
    for (int i = 0; i < 8; i++){
        int q = t + 512*i;
        int kd = q >> 4, jf = q & 15;
        float4 v = *(const float4*)(wbase + kd*64 + jf*4);
        half4 h, l;
        h.x = (_Float16)v.x; h.y = (_Float16)v.y; h.z = (_Float16)v.z; h.w = (_Float16)v.w;
        l.x = (_Float16)(v.x - (float)h.x); l.y = (_Float16)(v.y - (float)h.y);
        l.z = (_Float16)(v.z - (float)h.z); l.w = (_Float16)(v.w - (float)h.w);
        int kdt = kd >> 4, rowin = kd & 15;
        int j0 = jf*4;
        int kk = j0 >> 5, jb = (j0 & 31) >> 3, e0 = j0 & 7;
        int lane = rowin + 16*jb;
        int base = 8192 + ((kdt*2 + kk)*2)*512 + lane*8 + e0;
        *(half4*)(lds + base)       = h;
        *(half4*)(lds + base + 512) = l;
    }
    __syncthreads();

    int w    = t >> 6;
    int lane = t & 63;
    int wbt  = w >> 1;
    int kdh  = w & 1;

    half8 a[2][2];
    #pragma unroll
    for (int kk = 0; kk < 2; kk++)
        #pragma unroll
        for (int hl = 0; hl < 2; hl++)
            a[kk][hl] = *(half8*)(lds + ((wbt*2 + kk)*2 + hl)*512 + lane*8);

    int brow = (lane >> 4) * 4;
    int bcol = lane & 15;

    #pragma unroll
    for (int kdti = 0; kdti < 8; kdti++){
        int kdt = kdh*8 + kdti;
        const _Float16* wb0 = lds + 8192 + ((kdt*2 + 0)*2)*512 + lane*8;
        const _Float16* wb1 = lds + 8192 + ((kdt*2 + 1)*2)*512 + lane*8;
        half8 bh0 = *(half8*)(wb0);
        half8 bl0 = *(half8*)(wb0 + 512);
        half8 bh1 = *(half8*)(wb1);
        half8 bl1 = *(half8*)(wb1 + 512);
        f32x4 acc = {0.f, 0.f, 0.f, 0.f};
        acc = __builtin_amdgcn_mfma_f32_16x16x32_f16(a[0][0], bh0, acc, 0, 0, 0);
        acc = __builtin_amdgcn_mfma_f32_16x16x32_f16(a[0][0], bl0, acc, 0, 0, 0);
        acc = __builtin_amdgcn_mfma_f32_16x16x32_f16(a[0][1], bh0, acc, 0, 0, 0);
        acc = __builtin_amdgcn_mfma_f32_16x16x32_f16(a[1][0], bh1, acc, 0, 0, 0);
        acc = __builtin_amdgcn_mfma_f32_16x16x32_f16(a[1][0], bl1, acc, 0, 0, 0);
        acc = __builtin_amdgcn_mfma_f32_16x16x32_f16(a[1][1], bh1, acc, 0, 0, 0);
        int kd = kdt*16 + bcol;
        #pragma unroll
        for (int r = 0; r < 4; r++){
            int rl = wbt*16 + brow + r;
            if (rl < rows)
                hat[((size_t)(btile*64 + rl)*SS + s)*256 + kd] = acc[r];
        }
    }
}

// Dynamic routing, 3 iters — shuffle-free dual-mapping.
// 256 thr per b: mapping A (thread=s, cw[4] in regs, serial softmax),
// mapping B (thread=(phase,q4), coalesced cap streaming + LDS combine).
__global__ void __launch_bounds__(256) k_route(const float* __restrict__ eb,
                                               const float* __restrict__ mask_,
                                               const float* __restrict__ ws,
                                               const float* __restrict__ hat,
                                               float* __restrict__ out, int b0){
    int bl = blockIdx.x;
    int b = b0 + bl;
    int t = threadIdx.x;
    int lane = t & 63;
    __shared__ float swL[4*SWP];
    __shared__ float sdata[4*256];
    __shared__ float capL[256];
    __shared__ float logits[4];
    __shared__ int kms;

    // mapping A state (thread = s = t)
    int s = t;
    float cw0 = 0.f, cw1 = 0.f, cw2 = 0.f, cw3 = 0.f;
    float fac = ws[OFF_FAC + (size_t)b*SS + s];
    float mk  = mask_[(size_t)b*SS + s];
    // mapping B ids
    int phase = t >> 6, q4 = t & 63, kq = q4 >> 4;
    // mapping C (k,d) for squash/epilogue
    int kk2 = t >> 6, dd = t & 63;
    const float4* hb4 = (const float4*)(hat + (size_t)bl*65536);
    float capv = 0.f;

    for (int it = 0; it < 3; ++it){
        // A1: per-thread softmax over k + mask
        float m = fmaxf(fmaxf(cw0, cw1), fmaxf(cw2, cw3));
        float e0 = expf(cw0-m), e1 = expf(cw1-m), e2 = expf(cw2-m), e3 = expf(cw3-m);
        float inv = 1.f / (e0+e1+e2+e3);
        float mm = (mk == 0.f) ? 0.f : inv;
        swL[0*SWP+s] = e0*mm; swL[1*SWP+s] = e1*mm;
        swL[2*SWP+s] = e2*mm; swL[3*SWP+s] = e3*mm;
        __syncthreads();

        // B: cap accumulation (coalesced hat stream, no shuffles)
        float4 acc = {0.f, 0.f, 0.f, 0.f};
        #pragma unroll 8
        for (int i = 0; i < 64; i++){
            int ss = i*4 + phase;
            float swv = swL[kq*SWP + ss];
            float4 hv = hb4[ss*64 + q4];
            acc.x += swv*hv.x; acc.y += swv*hv.y;
            acc.z += swv*hv.z; acc.w += swv*hv.w;
        }
        *(float4*)(sdata + phase*256 + q4*4) = acc;
        __syncthreads();
        float cp = sdata[0*256 + t] + sdata[1*256 + t]
                 + sdata[2*256 + t] + sdata[3*256 + t];
        // squash (wave == k)
        float q = cp*cp;
        #pragma unroll
        for (int off = 1; off < 64; off <<= 1) q += __shfl_xor(q, off);
        float sc = q / ((1.f + q) * sqrtf(q + 1e-9f));
        capv = sc * cp;
        capL[t] = capv;
        __syncthreads();

        if (it < 2){
            // A2: delta, per-thread serial dot over capL broadcast
            const float4* hrow = hb4 + (size_t)s*64;
            float d0 = 0.f, d1 = 0.f, d2 = 0.f, d3 = 0.f;
            #pragma unroll
            for (int j = 0; j < 16; j++){
                float4 h0 = hrow[j],      c0 = *(const float4*)(capL + j*4);
                float4 h1 = hrow[16 + j], c1 = *(const float4*)(capL + 64 + j*4);
                float4 h2 = hrow[32 + j], c2 = *(const float4*)(capL + 128 + j*4);
                float4 h3 = hrow[48 + j], c3 = *(const float4*)(capL + 192 + j*4);
                d0 += h0.x*c0.x + h0.y*c0.y + h0.z*c0.z + h0.w*c0.w;
                d1 += h1.x*c1.x + h1.y*c1.y + h1.z*c1.z + h1.w*c1.w;
                d2 += h2.x*c2.x + h2.y*c2.y + h2.z*c2.z + h2.w*c2.w;
                d3 += h3.x*c3.x + h3.y*c3.y + h3.z*c3.z + h3.w*c3.w;
            }
            cw0 += d0*fac; cw1 += d1*fac; cw2 += d2*fac; cw3 += d3*fac;
        }
    }

    // epilogue
    out[(size_t)b*256 + t] = capv;
    float qq = capv * eb[(size_t)b*DD + dd];
    #pragma unroll
    for (int off = 1; off < 64; off <<= 1) qq += __shfl_xor(qq, off);
    if (lane == 0) logits[kk2] = qq;
    __syncthreads();
    if (t == 0){
        float best = logits[0]; int km = 0;
        for (int kk = 1; kk < 4; kk++) if (logits[kk] > best){ best = logits[kk]; km = kk; }
        kms = km;
    }
    __syncthreads();
    if (t < 64) out[(size_t)BB*256 + (size_t)b*64 + t] = capL[kms*64 + t];
}

__global__ void k_final(const float* __restrict__ phase, const float* __restrict__ ratio,
                        float* ws, float* __restrict__ out){
    if (threadIdx.x == 0){
        float r2a = 0.f, r2b = 0.f;
        for (int g = 0; g < NG; g++){ r2a += ratio[g]*ratio[g]; r2b += phase[g]*phase[g]; }
        float reg2 = sqrtf(r2a) + sqrtf(r2b) / 100000.0f;
        float reg1 = sqrtf(ws[OFF_SCAL + 4]);
        out[(size_t)BB*256 + (size_t)BB*64] = 0.1f*reg1 + reg2 + 1.0f/reg1 + 0.1f/reg2;
    }
}

extern "C" void kernel_launch(void* const* d_in, const int* in_sizes, int n_in,
                              void* d_out, int out_size, void* d_ws, size_t ws_size,
                              hipStream_t stream){
    const float* Xh = (const float*)d_in[0];
    const float* eb = (const float*)d_in[1];
    const float* tb = (const float*)d_in[2];
    const float* th = (const float*)d_in[3];
    const float* mk = (const float*)d_in[4];
    const float* W1 = (const float*)d_in[5];
    const float* b1 = (const float*)d_in[6];
    const float* W2 = (const float*)d_in[7];
    const float* b2 = (const float*)d_in[8];
    const float* ph = (const float*)d_in[9];
    const float* ta = (const float*)d_in[10];
    const float* ra = (const float*)d_in[11];
    const float* ge = (const float*)d_in[12];
    const float* wb = (const float*)d_in[13];
    float* out = (float*)d_out;
    float* ws  = (float*)d_ws;

    hipLaunchKernelGGL(k_init,   dim3(1),    dim3(64),  0, stream, ws);
    hipLaunchKernelGGL(k_min,    dim3(256),  dim3(256), 0, stream, tb, th, ws);
    hipLaunchKernelGGL(k_tables, dim3((PMAX+TPB-1)/TPB), dim3(128), 0, stream, W1, ws);
    hipLaunchKernelGGL(k_gtb,    dim3(BB),   dim3(128), 0, stream, tb, W1, b1, ws);
    hipLaunchKernelGGL(k_factor, dim3(2*BB), dim3(256), 0, stream, tb, th, W2, b2, ws);
    hipLaunchKernelGGL(k_gate,   dim3(BB),   dim3(256), 0, stream, Xh, th, ph, ta, ra, ge, ws);

    long wfloats  = (long)(ws_size / sizeof(float));
    long hatavail = wfloats - (long)OFF_HAT;
    int CH = (int)(hatavail / 65536);      // batches per chunk
    if (CH > BB) CH = BB;
    if (CH >= 128) CH &= ~127;             // keep 64-row tiles full per chunk
    if (CH < 1)  CH = 1;
    float* hatbuf = ws + OFF_HAT;
    for (int c0 = 0; c0 < BB; c0 += CH){
        int nb = BB - c0; if (nb > CH) nb = CH;
        int nbt = (nb + 63) / 64;
        hipLaunchKernelGGL(k_hat,   dim3(nbt, 256), dim3(512), 0, stream, Xh, wb, hatbuf, c0, nb);
        hipLaunchKernelGGL(k_route, dim3(nb),       dim3(256), 0, stream, eb, mk, ws, hatbuf, out, c0);
    }
    hipLaunchKernelGGL(k_final, dim3(1), dim3(64), 0, stream, ph, ra, ws, out);
}

// Round 11
// 553.299 us; speedup vs baseline: 1.2319x; 1.2319x over previous
//
#include <hip/hip_runtime.h>
#include <math.h>
#include <limits.h>

#define BB 1024
#define SS 256
#define DD 64
#define NI 4
#define NG 8
#define TE_N 100
#define PMAX 57420
#define ROWP 100            // table row stride (400B, float4-aligned)
#define TPB 16              // positions per k_tables block

typedef _Float16 half8 __attribute__((ext_vector_type(8)));
typedef _Float16 half4 __attribute__((ext_vector_type(4)));
typedef float f32x4 __attribute__((ext_vector_type(4)));

// ws layout (float units) — fixed region first, hat chunk buffer last
#define OFF_FTH   ((size_t)0)
#define OFF_FDF   ((size_t)PMAX*ROWP)                 //  5,742,000
#define OFF_GTB   ((size_t)2*PMAX*ROWP)               // 11,484,000
#define OFF_FAC   (OFF_GTB + (size_t)BB*ROWP)         // 11,586,400
#define OFF_SCAL  (OFF_FAC + (size_t)BB*SS)           // 11,848,544
#define OFF_HAT   (OFF_SCAL + 32)                     // 11,848,576

__global__ void k_init(float* ws){
    if (threadIdx.x == 0){
        int* mi = (int*)(ws + OFF_SCAL);
        mi[0] = INT_MAX; mi[1] = INT_MAX; mi[2] = INT_MAX;
        ws[OFF_SCAL + 4] = 0.0f;
    }
}

__global__ void k_min(const float* __restrict__ tb, const float* __restrict__ th, float* ws){
    int gid = blockIdx.x * blockDim.x + threadIdx.x;
    int stride = gridDim.x * blockDim.x;
    int m0 = INT_MAX, m1 = INT_MAX, m2 = INT_MAX;
    for (int i = gid; i < BB*SS; i += stride){
        float t  = th[i];
        float t2 = tb[i >> 8];
        int i1 = (int)(t / 10000.0f);
        int i2 = (int)((t2 - t) / 10000.0f);
        m1 = min(m1, i1);
        m2 = min(m2, i2);
    }
    if (gid < BB) m0 = (int)(tb[gid] / 10000.0f);
    #pragma unroll
    for (int off = 1; off < 64; off <<= 1){
        m0 = min(m0, __shfl_xor(m0, off));
        m1 = min(m1, __shfl_xor(m1, off));
        m2 = min(m2, __shfl_xor(m2, off));
    }
    if ((threadIdx.x & 63) == 0){
        int* mi = (int*)(ws + OFF_SCAL);
        atomicMin(mi + 0, m0);
        atomicMin(mi + 1, m1);
        atomicMin(mi + 2, m2);
    }
}

// f_th[p,j] = TE(p) . W1[100:200, j] ; f_diff[p,j] = TE(p) . W1[200:300, j]
__global__ void k_tables(const float* __restrict__ W1, float* ws){
    int pbase = blockIdx.x * TPB;
    int t = threadIdx.x;                  // 128
    __shared__ float te[TPB][TE_N];
    for (int idx = t; idx < TPB*50; idx += 128){
        int pp = idx / 50, h = idx - pp*50;
        double div = exp((double)h * -0.09210340371976184); // -ln(10000)/100
        double a = (double)(pbase + pp) * div;
        te[pp][2*h]   = (float)sin(a);
        te[pp][2*h+1] = (float)cos(a);
    }
    __syncthreads();
    if (t < TE_N){
        float a1[TPB], a2[TPB];
        #pragma unroll
        for (int pp = 0; pp < TPB; pp++){ a1[pp] = 0.f; a2[pp] = 0.f; }
        for (int i = 0; i < TE_N; i++){
            float w1v = W1[(100+i)*100 + t];
            float w2v = W1[(200+i)*100 + t];
            #pragma unroll
            for (int pp = 0; pp < TPB; pp++){
                float v = te[pp][i];
                a1[pp] += v * w1v;
                a2[pp] += v * w2v;
            }
        }
        for (int pp = 0; pp < TPB; pp++){
            int p = pbase + pp;
            if (p < PMAX){
                ws[OFF_FTH + (size_t)p*ROWP + t] = a1[pp];
                ws[OFF_FDF + (size_t)p*ROWP + t] = a2[pp];
            }
        }
    }
}

// g_tb[b,j] = TE(pos_tb(b)) . W1[0:100, j] + b1[j]
__global__ void k_gtb(const float* __restrict__ tb, const float* __restrict__ W1,
                      const float* __restrict__ b1, float* ws){
    int b = blockIdx.x;
    int t = threadIdx.x;
    const int* mi = (const int*)(ws + OFF_SCAL);
    int p = (int)(tb[b] / 10000.0f) - mi[0];
    __shared__ float te[TE_N];
    if (t < TE_N/2){
        double div = exp((double)t * -0.09210340371976184);
        double a = (double)p * div;
        te[2*t]   = (float)sin(a);
        te[2*t+1] = (float)cos(a);
    }
    __syncthreads();
    if (t < TE_N){
        float a1 = b1[t];
        for (int i = 0; i < TE_N; i++) a1 += te[i] * W1[i*100 + t];
        ws[OFF_GTB + (size_t)b*ROWP + t] = a1;
    }
}

// tf[b,s] = sigmoid(MLP) — wave per (b,s) pair, coalesced row gathers.
__global__ void __launch_bounds__(256) k_factor(const float* __restrict__ tbatch,
                         const float* __restrict__ th_, const float* __restrict__ W2,
                         const float* __restrict__ b2, float* ws){
    int b  = blockIdx.x >> 1;
    int sh = blockIdx.x & 1;
    int t  = threadIdx.x;
    int lane = t & 63, wv = t >> 6;
    __shared__ float sgtb[TE_N];
    if (t < TE_N) sgtb[t] = ws[OFF_GTB + (size_t)b*ROWP + t];
    __syncthreads();

    bool tail = (lane < 36);
    float w2a = W2[lane];
    float w2b = tail ? W2[64 + lane] : 0.f;
    float ga  = sgtb[lane];
    float gb  = tail ? sgtb[64 + lane] : 0.f;
    float bias = b2[0];

    int sbase = sh*128 + wv*32;
    const int* mi = (const int*)(ws + OFF_SCAL);
    int pth = 0, pdf = 0;
    if (lane < 32){
        float thv = th_[(size_t)b*SS + sbase + lane];
        float tbv = tbatch[b];
        pth = (int)(thv / 10000.0f) - mi[1];
        pdf = (int)((tbv - thv) / 10000.0f) - mi[2];
        pth = min(max(pth, 0), PMAX-1);
        pdf = min(max(pdf, 0), PMAX-1);
    }

    float tfkeep = 0.f;
    float r1acc  = 0.f;
    #pragma unroll 4
    for (int i = 0; i < 32; i++){
        int p1 = __shfl(pth, i);
        int p2 = __shfl(pdf, i);
        const float* r1 = ws + OFF_FTH + (size_t)p1*ROWP;
        const float* r2 = ws + OFF_FDF + (size_t)p2*ROWP;
        float a  = r1[lane];
        float c  = r2[lane];
        float a2 = tail ? r1[64 + lane] : 0.f;
        float c2 = tail ? r2[64 + lane] : 0.f;
        float h = fmaxf(ga + a + c, 0.f) * w2a;
        if (tail) h += fmaxf(gb + a2 + c2, 0.f) * w2b;
        #pragma unroll
        for (int off = 1; off < 64; off <<= 1) h += __shfl_xor(h, off);
        float tf = 1.f / (1.f + expf(-(h + bias)));
        if (lane == i){ tfkeep = tf; r1acc += tf*tf; }
    }
    if (lane < 32) ws[OFF_FAC + (size_t)b*SS + sbase + lane] = tfkeep;
    #pragma unroll
    for (int off = 1; off < 64; off <<= 1) r1acc += __shfl_xor(r1acc, off);
    if (lane == 0) atomicAdd(ws + OFF_SCAL + 4, r1acc);
}

// gate factor: ws[OFF_FAC + b*SS + s] += sum_g softmax_g(X.gate_emb) * gate(th)
__global__ void __launch_bounds__(256) k_gate(const float* __restrict__ X,
      const float* __restrict__ th_, const float* __restrict__ phase,
      const float* __restrict__ tao, const float* __restrict__ ratio,
      const float* __restrict__ ge, float* ws){
    __shared__ float sge[NG][DD];
    int t = threadIdx.x;
    for (int i = t; i < DD*NG; i += 256) sge[i & 7][i >> 3] = ge[i];
    __syncthreads();
    int gid = blockIdx.x * 256 + t;

    float lg[NG];
    #pragma unroll
    for (int g = 0; g < NG; g++) lg[g] = 0.f;
    const float4* xr = (const float4*)(X + (size_t)gid*DD);
    #pragma unroll 4
    for (int dc = 0; dc < 16; dc++){
        float4 xv = xr[dc];
        #pragma unroll
        for (int g = 0; g < NG; g++){
            lg[g] += xv.x*sge[g][dc*4+0] + xv.y*sge[g][dc*4+1]
                   + xv.z*sge[g][dc*4+2] + xv.w*sge[g][dc*4+3];
        }
    }
    float mx = lg[0];
    #pragma unroll
    for (int g = 1; g < NG; g++) mx = fmaxf(mx, lg[g]);
    float thv = th_[gid];
    float es = 0.f, gf = 0.f;
    #pragma unroll
    for (int g = 0; g < NG; g++){
        float e = expf(lg[g] - mx);
        es += e;
        float phv = fmodf(thv - phase[g], tao[g]) / tao[g];
        float gv = (phv < ratio[g]) ? fmaxf(sinf(3.14159f*phv/ratio[g]), 0.f) : 0.1f*phv;
        gf += e * gv;
    }
    ws[OFF_FAC + gid] += gf / es;
}

// hat[bl,s,kd] = sum_j Wb[s,kd,j] * X[b0+bl,s,j]  — split-fp16 MFMA.
__global__ void __launch_bounds__(512, 2)
k_hat(const float* __restrict__ X, const float* __restrict__ Wb,
      float* __restrict__ hat, int b0, int nb){
    int btile = blockIdx.x;      // 64-row b tile
    int s     = blockIdx.y;
    int t     = threadIdx.x;     // 512
    int rows = nb - btile*64; if (rows > 64) rows = 64;

    __shared__ _Float16 lds[40960];   // 80 KB

    const float* xbase = X + ((size_t)(b0 + btile*64)*SS + s)*DD;
    #pragma unroll
    for (int i = 0; i < 2; i++){
        int q = t + 512*i;
        int r = q >> 4, jf = q & 15;
        float4 v;
        if (r < rows) v = *(const float4*)(xbase + (size_t)r*SS*DD + jf*4);
        else { v.x = 0.f; v.y = 0.f; v.z = 0.f; v.w = 0.f; }
        half4 h, l;
        h.x = (_Float16)v.x; h.y = (_Float16)v.y; h.z = (_Float16)v.z; h.w = (_Float16)v.w;
        l.x = (_Float16)(v.x - (float)h.x); l.y = (_Float16)(v.y - (float)h.y);
        l.z = (_Float16)(v.z - (float)h.z); l.w = (_Float16)(v.w - (float)h.w);
        int bt = r >> 4, rowin = r & 15;
        int j0 = jf*4;
        int kk = j0 >> 5, jb = (j0 & 31) >> 3, e0 = j0 & 7;
        int lane = rowin + 16*jb;
        int base = ((bt*2 + kk)*2)*512 + lane*8 + e0;
        *(half4*)(lds + base)       = h;
        *(half4*)(lds + base + 512) = l;
    }
    const float* wbase = Wb + (size_t)s*16384;
    #pragma unroll
    for (int i = 0; i < 8; i++){
        int q = t + 512*i;
        int kd = q >> 4, jf = q & 15;
        float4 v = *(const float4*)(wbase + kd*64 + jf*4);
        half4 h, l;
        h.x = (_Float16)v.x; h.y = (_Float16)v.y; h.z = (_Float16)v.z; h.w = (_Float16)v.w;
        l.x = (_Float16)(v.x - (float)h.x); l.y = (_Float16)(v.y - (float)h.y);
        l.z = (_Float16)(v.z - (float)h.z); l.w = (_Float16)(v.w - (float)h.w);
        int kdt = kd >> 4, rowin = kd & 15;
        int j0 = jf*4;
        int kk = j0 >> 5, jb = (j0 & 31) >> 3, e0 = j0 & 7;
        int lane = rowin + 16*jb;
        int base = 8192 + ((kdt*2 + kk)*2)*512 + lane*8 + e0;
        *(half4*)(lds + base)       = h;
        *(half4*)(lds + base + 512) = l;
    }
    __syncthreads();

    int w    = t >> 6;
    int lane = t & 63;
    int wbt  = w >> 1;
    int kdh  = w & 1;

    half8 a[2][2];
    #pragma unroll
    for (int kk = 0; kk < 2; kk++)
        #pragma unroll
        for (int hl = 0; hl < 2; hl++)
            a[kk][hl] = *(half8*)(lds + ((wbt*2 + kk)*2 + hl)*512 + lane*8);

    int brow = (lane >> 4) * 4;
    int bcol = lane & 15;

    #pragma unroll
    for (int kdti = 0; kdti < 8; kdti++){
        int kdt = kdh*8 + kdti;
        const _Float16* wb0 = lds + 8192 + ((kdt*2 + 0)*2)*512 + lane*8;
        const _Float16* wb1 = lds + 8192 + ((kdt*2 + 1)*2)*512 + lane*8;
        half8 bh0 = *(half8*)(wb0);
        half8 bl0 = *(half8*)(wb0 + 512);
        half8 bh1 = *(half8*)(wb1);
        half8 bl1 = *(half8*)(wb1 + 512);
        f32x4 acc = {0.f, 0.f, 0.f, 0.f};
        acc = __builtin_amdgcn_mfma_f32_16x16x32_f16(a[0][0], bh0, acc, 0, 0, 0);
        acc = __builtin_amdgcn_mfma_f32_16x16x32_f16(a[0][0], bl0, acc, 0, 0, 0);
        acc = __builtin_amdgcn_mfma_f32_16x16x32_f16(a[0][1], bh0, acc, 0, 0, 0);
        acc = __builtin_amdgcn_mfma_f32_16x16x32_f16(a[1][0], bh1, acc, 0, 0, 0);
        acc = __builtin_amdgcn_mfma_f32_16x16x32_f16(a[1][0], bl1, acc, 0, 0, 0);
        acc = __builtin_amdgcn_mfma_f32_16x16x32_f16(a[1][1], bh1, acc, 0, 0, 0);
        int kd = kdt*16 + bcol;
        #pragma unroll
        for (int r = 0; r < 4; r++){
            int rl = wbt*16 + brow + r;
            if (rl < rows)
                hat[((size_t)(btile*64 + rl)*SS + s)*256 + kd] = acc[r];
        }
    }
}

// Dynamic routing, 3 iters. Lane map: k = bits 2,3; s-bits = {0,1,4,5}.
// s-butterfly masks {1,2} lower to DPP quad-perm (VALU pipe); {16,32} stay
// on the LDS pipe (plain __shfl_xor — verified semantics). The s-bit pairing
// order (bit0,bit1,bit2,bit3) is IDENTICAL to the round-8 kernel, so the
// floating-point tree is bit-identical to the known-good version.
__global__ void __launch_bounds__(1024) k_route(const float* __restrict__ eb,
                                                const float* __restrict__ mask_,
                                                const float* __restrict__ ws,
                                                const float* __restrict__ hat,
                                                float* __restrict__ out, int b0){
    int bl = blockIdx.x;
    int b = b0 + bl;
    int t = threadIdx.x;
    int lane = t & 63, wv = t >> 6;
    int k = (lane >> 2) & 3;
    int s_local = (lane & 3) | (((lane >> 4) & 3) << 2);
    int s = wv * 16 + s_local;
    __shared__ float part[16][4][64];
    __shared__ float capl[4][68];
    __shared__ float logits[4];
    __shared__ int kms;

    float hat_r[64];
    const float4* hsrc = (const float4*)(hat + (size_t)bl*65536 + ((size_t)s*4 + k)*64);
    #pragma unroll
    for (int jc = 0; jc < 16; jc++){
        float4 v = hsrc[jc];
        hat_r[4*jc] = v.x; hat_r[4*jc+1] = v.y; hat_r[4*jc+2] = v.z; hat_r[4*jc+3] = v.w;
    }
    float fac = ws[OFF_FAC + (size_t)b*SS + s];
    float mk = mask_[(size_t)b*SS + s];
    float cw = 0.f;
    float capv = 0.f;

    for (int it = 0; it < 3; ++it){
        float sw;
        if (it == 0){
            sw = (mk == 0.f) ? 0.f : 0.25f;
        } else {
            // softmax over k (lane bits 2,3): masks 4, 8
            float m = fmaxf(cw, __shfl_xor(cw, 4)); m = fmaxf(m, __shfl_xor(m, 8));
            float e = expf(cw - m);
            float ssum = e + __shfl_xor(e, 4); ssum += __shfl_xor(ssum, 8);
            sw = (mk == 0.f) ? 0.f : (e / ssum);
        }

        // s-reduction: masks 1,2 (DPP quad-perm), 16, 32 (LDS pipe)
        #pragma unroll
        for (int c = 0; c < 4; c++){
            float tmp[16];
            #pragma unroll
            for (int i = 0; i < 16; i++) tmp[i] = sw * hat_r[c*16 + i];
            #pragma unroll
            for (int i = 0; i < 16; i++) tmp[i] += __shfl_xor(tmp[i], 1);
            #pragma unroll
            for (int i = 0; i < 16; i++) tmp[i] += __shfl_xor(tmp[i], 2);
            #pragma unroll
            for (int i = 0; i < 16; i++) tmp[i] += __shfl_xor(tmp[i], 16);
            #pragma unroll
            for (int i = 0; i < 16; i++) tmp[i] += __shfl_xor(tmp[i], 32);
            if ((lane & 0x33) == 0){
                float* dst = &part[wv][lane >> 2][c*16];
                #pragma unroll
                for (int i = 0; i < 4; i++)
                    ((float4*)dst)[i] = make_float4(tmp[4*i], tmp[4*i+1], tmp[4*i+2], tmp[4*i+3]);
            }
        }
        __syncthreads();
        if (t < 256){
            int k2 = t >> 6, d = t & 63;
            float cp = 0.f;
            #pragma unroll
            for (int w2 = 0; w2 < 16; w2++) cp += part[w2][k2][d];
            float q = cp * cp;
            #pragma unroll
            for (int msk = 1; msk < 64; msk <<= 1) q += __shfl_xor(q, msk);
            float sc = q / ((1.f + q) * sqrtf(q + 1e-9f));
            capv = sc * cp;
            capl[k2][d] = capv;
        }
        __syncthreads();
        if (it < 2){
            const float4* cp4 = (const float4*)&capl[k][0];
            float dot = 0.f;
            #pragma unroll
            for (int jc = 0; jc < 16; jc++){
                float4 v = cp4[jc];
                dot += hat_r[4*jc]*v.x + hat_r[4*jc+1]*v.y + hat_r[4*jc+2]*v.z + hat_r[4*jc+3]*v.w;
            }
            cw += dot * fac;
        }
        __syncthreads();
    }

    if (t < 256){
        int k2 = t >> 6, d = t & 63;
        out[(size_t)b*256 + t] = capv;
        float qq = capv * eb[(size_t)b*DD + d];
        #pragma unroll
        for (int msk = 1; msk < 64; msk <<= 1) qq += __shfl_xor(qq, msk);
        if (lane == 0) logits[k2] = qq;
    }
    __syncthreads();
    if (t == 0){
        float best = logits[0]; int km = 0;
        for (int kk = 1; kk < 4; kk++) if (logits[kk] > best){ best = logits[kk]; km = kk; }
        kms = km;
    }
    __syncthreads();
    if (t < 64) out[(size_t)BB*256 + (size_t)b*64 + t] = capl[kms][t];
}

__global__ void k_final(const float* __restrict__ phase, const float* __restrict__ ratio,
                        float* ws, float* __restrict__ out){
    if (threadIdx.x == 0){
        float r2a = 0.f, r2b = 0.f;
        for (int g = 0; g < NG; g++){ r2a += ratio[g]*ratio[g]; r2b += phase[g]*phase[g]; }
        float reg2 = sqrtf(r2a) + sqrtf(r2b) / 100000.0f;
        float reg1 = sqrtf(ws[OFF_SCAL + 4]);
        out[(size_t)BB*256 + (size_t)BB*64] = 0.1f*reg1 + reg2 + 1.0f/reg1 + 0.1f/reg2;
    }
}

extern "C" void kernel_launch(void* const* d_in, const int* in_sizes, int n_in,
                              void* d_out, int out_size, void* d_ws, size_t ws_size,
                              hipStream_t stream){
    const float* Xh = (const float*)d_in[0];
    const float* eb = (const float*)d_in[1];
    const float* tb = (const float*)d_in[2];
    const float* th = (const float*)d_in[3];
    const float* mk = (const float*)d_in[4];
    const float* W1 = (const float*)d_in[5];
    const float* b1 = (const float*)d_in[6];
    const float* W2 = (const float*)d_in[7];
    const float* b2 = (const float*)d_in[8];
    const float* ph = (const float*)d_in[9];
    const float* ta = (const float*)d_in[10];
    const float* ra = (const float*)d_in[11];
    const float* ge = (const float*)d_in[12];
    const float* wb = (const float*)d_in[13];
    float* out = (float*)d_out;
    float* ws  = (float*)d_ws;

    hipLaunchKernelGGL(k_init,   dim3(1),    dim3(64),  0, stream, ws);
    hipLaunchKernelGGL(k_min,    dim3(256),  dim3(256), 0, stream, tb, th, ws);
    hipLaunchKernelGGL(k_tables, dim3((PMAX+TPB-1)/TPB), dim3(128), 0, stream, W1, ws);
    hipLaunchKernelGGL(k_gtb,    dim3(BB),   dim3(128), 0, stream, tb, W1, b1, ws);
    hipLaunchKernelGGL(k_factor, dim3(2*BB), dim3(256), 0, stream, tb, th, W2, b2, ws);
    hipLaunchKernelGGL(k_gate,   dim3(BB),   dim3(256), 0, stream, Xh, th, ph, ta, ra, ge, ws);

    long wfloats  = (long)(ws_size / sizeof(float));
    long hatavail = wfloats - (long)OFF_HAT;
    int CH = (int)(hatavail / 65536);      // batches per chunk
    if (CH > BB) CH = BB;
    if (CH >= 128) CH &= ~127;             // keep 64-row tiles full per chunk
    if (CH < 1)  CH = 1;
    float* hatbuf = ws + OFF_HAT;
    for (int c0 = 0; c0 < BB; c0 += CH){
        int nb = BB - c0; if (nb > CH) nb = CH;
        int nbt = (nb + 63) / 64;
        hipLaunchKernelGGL(k_hat,   dim3(nbt, 256), dim3(512),  0, stream, Xh, wb, hatbuf, c0, nb);
        hipLaunchKernelGGL(k_route, dim3(nb),       dim3(1024), 0, stream, eb, mk, ws, hatbuf, out, c0);
    }
    hipLaunchKernelGGL(k_final, dim3(1), dim3(64), 0, stream, ph, ra, ws, out);
}

// Round 12
// 493.571 us; speedup vs baseline: 1.3810x; 1.1210x over previous
//
#include <hip/hip_runtime.h>
#include <math.h>
#include <limits.h>

#define BB 1024
#define SS 256
#define DD 64
#define NI 4
#define NG 8
#define TE_N 100
#define PMAX 57420
#define ROWP 100            // table row stride (400B, float4-aligned)
#define TPB 16              // positions per k_tables block

typedef _Float16 half8 __attribute__((ext_vector_type(8)));
typedef _Float16 half4 __attribute__((ext_vector_type(4)));
typedef float f32x4 __attribute__((ext_vector_type(4)));

// ws layout (float units) — fixed region first, hat chunk buffer last
#define OFF_FTH   ((size_t)0)
#define OFF_FDF   ((size_t)PMAX*ROWP)                 //  5,742,000
#define OFF_GTB   ((size_t)2*PMAX*ROWP)               // 11,484,000
#define OFF_FAC   (OFF_GTB + (size_t)BB*ROWP)         // 11,586,400
#define OFF_SCAL  (OFF_FAC + (size_t)BB*SS)           // 11,848,544
#define OFF_HAT   (OFF_SCAL + 32)                     // 11,848,576

// pairwise-sum helpers on the VALU pipe (DPP quad_perm) and LDS pipe (swizzle).
// dpp quad_perm[1,0,3,2]=0xB1 (xor 1), [2,3,0,1]=0x4E (xor 2) — exchanges the
// same two lanes as __shfl_xor, so the resulting sums are bit-identical.
__device__ inline float dpp_add_xor1(float x){
    int i = __builtin_bit_cast(int, x);
    int p = __builtin_amdgcn_update_dpp(i, i, 0xB1, 0xF, 0xF, true);
    return x + __builtin_bit_cast(float, p);
}
__device__ inline float dpp_add_xor2(float x){
    int i = __builtin_bit_cast(int, x);
    int p = __builtin_amdgcn_update_dpp(i, i, 0x4E, 0xF, 0xF, true);
    return x + __builtin_bit_cast(float, p);
}
// ds_swizzle BitMode offset 0x401F = xor lane^16 within each 32-lane half
__device__ inline float swz_add_xor16(float x){
    int i = __builtin_bit_cast(int, x);
    int p = __builtin_amdgcn_ds_swizzle(i, 0x401F);
    return x + __builtin_bit_cast(float, p);
}

__global__ void k_init(float* ws){
    if (threadIdx.x == 0){
        int* mi = (int*)(ws + OFF_SCAL);
        mi[0] = INT_MAX; mi[1] = INT_MAX; mi[2] = INT_MAX;
        ws[OFF_SCAL + 4] = 0.0f;
    }
}

__global__ void k_min(const float* __restrict__ tb, const float* __restrict__ th, float* ws){
    int gid = blockIdx.x * blockDim.x + threadIdx.x;
    int stride = gridDim.x * blockDim.x;
    int m0 = INT_MAX, m1 = INT_MAX, m2 = INT_MAX;
    for (int i = gid; i < BB*SS; i += stride){
        float t  = th[i];
        float t2 = tb[i >> 8];
        int i1 = (int)(t / 10000.0f);
        int i2 = (int)((t2 - t) / 10000.0f);
        m1 = min(m1, i1);
        m2 = min(m2, i2);
    }
    if (gid < BB) m0 = (int)(tb[gid] / 10000.0f);
    #pragma unroll
    for (int off = 1; off < 64; off <<= 1){
        m0 = min(m0, __shfl_xor(m0, off));
        m1 = min(m1, __shfl_xor(m1, off));
        m2 = min(m2, __shfl_xor(m2, off));
    }
    if ((threadIdx.x & 63) == 0){
        int* mi = (int*)(ws + OFF_SCAL);
        atomicMin(mi + 0, m0);
        atomicMin(mi + 1, m1);
        atomicMin(mi + 2, m2);
    }
}

// f_th[p,j] = TE(p) . W1[100:200, j] ; f_diff[p,j] = TE(p) . W1[200:300, j]
__global__ void k_tables(const float* __restrict__ W1, float* ws){
    int pbase = blockIdx.x * TPB;
    int t = threadIdx.x;                  // 128
    __shared__ float te[TPB][TE_N];
    for (int idx = t; idx < TPB*50; idx += 128){
        int pp = idx / 50, h = idx - pp*50;
        double div = exp((double)h * -0.09210340371976184); // -ln(10000)/100
        double a = (double)(pbase + pp) * div;
        te[pp][2*h]   = (float)sin(a);
        te[pp][2*h+1] = (float)cos(a);
    }
    __syncthreads();
    if (t < TE_N){
        float a1[TPB], a2[TPB];
        #pragma unroll
        for (int pp = 0; pp < TPB; pp++){ a1[pp] = 0.f; a2[pp] = 0.f; }
        for (int i = 0; i < TE_N; i++){
            float w1v = W1[(100+i)*100 + t];
            float w2v = W1[(200+i)*100 + t];
            #pragma unroll
            for (int pp = 0; pp < TPB; pp++){
                float v = te[pp][i];
                a1[pp] += v * w1v;
                a2[pp] += v * w2v;
            }
        }
        for (int pp = 0; pp < TPB; pp++){
            int p = pbase + pp;
            if (p < PMAX){
                ws[OFF_FTH + (size_t)p*ROWP + t] = a1[pp];
                ws[OFF_FDF + (size_t)p*ROWP + t] = a2[pp];
            }
        }
    }
}

// g_tb[b,j] = TE(pos_tb(b)) . W1[0:100, j] + b1[j]
__global__ void k_gtb(const float* __restrict__ tb, const float* __restrict__ W1,
                      const float* __restrict__ b1, float* ws){
    int b = blockIdx.x;
    int t = threadIdx.x;
    const int* mi = (const int*)(ws + OFF_SCAL);
    int p = (int)(tb[b] / 10000.0f) - mi[0];
    __shared__ float te[TE_N];
    if (t < TE_N/2){
        double div = exp((double)t * -0.09210340371976184);
        double a = (double)p * div;
        te[2*t]   = (float)sin(a);
        te[2*t+1] = (float)cos(a);
    }
    __syncthreads();
    if (t < TE_N){
        float a1 = b1[t];
        for (int i = 0; i < TE_N; i++) a1 += te[i] * W1[i*100 + t];
        ws[OFF_GTB + (size_t)b*ROWP + t] = a1;
    }
}

// tf[b,s] = sigmoid(MLP) — wave per (b,s) pair, coalesced row gathers.
__global__ void __launch_bounds__(256) k_factor(const float* __restrict__ tbatch,
                         const float* __restrict__ th_, const float* __restrict__ W2,
                         const float* __restrict__ b2, float* ws){
    int b  = blockIdx.x >> 1;
    int sh = blockIdx.x & 1;
    int t  = threadIdx.x;
    int lane = t & 63, wv = t >> 6;
    __shared__ float sgtb[TE_N];
    if (t < TE_N) sgtb[t] = ws[OFF_GTB + (size_t)b*ROWP + t];
    __syncthreads();

    bool tail = (lane < 36);
    float w2a = W2[lane];
    float w2b = tail ? W2[64 + lane] : 0.f;
    float ga  = sgtb[lane];
    float gb  = tail ? sgtb[64 + lane] : 0.f;
    float bias = b2[0];

    int sbase = sh*128 + wv*32;
    const int* mi = (const int*)(ws + OFF_SCAL);
    int pth = 0, pdf = 0;
    if (lane < 32){
        float thv = th_[(size_t)b*SS + sbase + lane];
        float tbv = tbatch[b];
        pth = (int)(thv / 10000.0f) - mi[1];
        pdf = (int)((tbv - thv) / 10000.0f) - mi[2];
        pth = min(max(pth, 0), PMAX-1);
        pdf = min(max(pdf, 0), PMAX-1);
    }

    float tfkeep = 0.f;
    float r1acc  = 0.f;
    #pragma unroll 4
    for (int i = 0; i < 32; i++){
        int p1 = __shfl(pth, i);
        int p2 = __shfl(pdf, i);
        const float* r1 = ws + OFF_FTH + (size_t)p1*ROWP;
        const float* r2 = ws + OFF_FDF + (size_t)p2*ROWP;
        float a  = r1[lane];
        float c  = r2[lane];
        float a2 = tail ? r1[64 + lane] : 0.f;
        float c2 = tail ? r2[64 + lane] : 0.f;
        float h = fmaxf(ga + a + c, 0.f) * w2a;
        if (tail) h += fmaxf(gb + a2 + c2, 0.f) * w2b;
        #pragma unroll
        for (int off = 1; off < 64; off <<= 1) h += __shfl_xor(h, off);
        float tf = 1.f / (1.f + expf(-(h + bias)));
        if (lane == i){ tfkeep = tf; r1acc += tf*tf; }
    }
    if (lane < 32) ws[OFF_FAC + (size_t)b*SS + sbase + lane] = tfkeep;
    #pragma unroll
    for (int off = 1; off < 64; off <<= 1) r1acc += __shfl_xor(r1acc, off);
    if (lane == 0) atomicAdd(ws + OFF_SCAL + 4, r1acc);
}

// gate factor: ws[OFF_FAC + b*SS + s] += sum_g softmax_g(X.gate_emb) * gate(th)
__global__ void __launch_bounds__(256) k_gate(const float* __restrict__ X,
      const float* __restrict__ th_, const float* __restrict__ phase,
      const float* __restrict__ tao, const float* __restrict__ ratio,
      const float* __restrict__ ge, float* ws){
    __shared__ float sge[NG][DD];
    int t = threadIdx.x;
    for (int i = t; i < DD*NG; i += 256) sge[i & 7][i >> 3] = ge[i];
    __syncthreads();
    int gid = blockIdx.x * 256 + t;

    float lg[NG];
    #pragma unroll
    for (int g = 0; g < NG; g++) lg[g] = 0.f;
    const float4* xr = (const float4*)(X + (size_t)gid*DD);
    #pragma unroll 4
    for (int dc = 0; dc < 16; dc++){
        float4 xv = xr[dc];
        #pragma unroll
        for (int g = 0; g < NG; g++){
            lg[g] += xv.x*sge[g][dc*4+0] + xv.y*sge[g][dc*4+1]
                   + xv.z*sge[g][dc*4+2] + xv.w*sge[g][dc*4+3];
        }
    }
    float mx = lg[0];
    #pragma unroll
    for (int g = 1; g < NG; g++) mx = fmaxf(mx, lg[g]);
    float thv = th_[gid];
    float es = 0.f, gf = 0.f;
    #pragma unroll
    for (int g = 0; g < NG; g++){
        float e = expf(lg[g] - mx);
        es += e;
        float phv = fmodf(thv - phase[g], tao[g]) / tao[g];
        float gv = (phv < ratio[g]) ? fmaxf(sinf(3.14159f*phv/ratio[g]), 0.f) : 0.1f*phv;
        gf += e * gv;
    }
    ws[OFF_FAC + gid] += gf / es;
}

// hat[bl,s,kd] = sum_j Wb[s,kd,j] * X[b0+bl,s,j]  — split-fp16 MFMA.
__global__ void __launch_bounds__(512, 2)
k_hat(const float* __restrict__ X, const float* __restrict__ Wb,
      float* __restrict__ hat, int b0, int nb){
    int btile = blockIdx.x;      // 64-row b tile
    int s     = blockIdx.y;
    int t     = threadIdx.x;     // 512
    int rows = nb - btile*64; if (rows > 64) rows = 64;

    __shared__ _Float16 lds[40960];   // 80 KB

    const float* xbase = X + ((size_t)(b0 + btile*64)*SS + s)*DD;
    #pragma unroll
    for (int i = 0; i < 2; i++){
        int q = t + 512*i;
        int r = q >> 4, jf = q & 15;
        float4 v;
        if (r < rows) v = *(const float4*)(xbase + (size_t)r*SS*DD + jf*4);
        else { v.x = 0.f; v.y = 0.f; v.z = 0.f; v.w = 0.f; }
        half4 h, l;
        h.x = (_Float16)v.x; h.y = (_Float16)v.y; h.z = (_Float16)v.z; h.w = (_Float16)v.w;
        l.x = (_Float16)(v.x - (float)h.x); l.y = (_Float16)(v.y - (float)h.y);
        l.z = (_Float16)(v.z - (float)h.z); l.w = (_Float16)(v.w - (float)h.w);
        int bt = r >> 4, rowin = r & 15;
        int j0 = jf*4;
        int kk = j0 >> 5, jb = (j0 & 31) >> 3, e0 = j0 & 7;
        int lane = rowin + 16*jb;
        int base = ((bt*2 + kk)*2)*512 + lane*8 + e0;
        *(half4*)(lds + base)       = h;
        *(half4*)(lds + base + 512) = l;
    }
    const float* wbase = Wb + (size_t)s*16384;
    #pragma unroll
    for (int i = 0; i < 8; i++){
        int q = t + 512*i;
        int kd = q >> 4, jf = q & 15;
        float4 v = *(const float4*)(wbase + kd*64 + jf*4);
        half4 h, l;
        h.x = (_Float16)v.x; h.y = (_Float16)v.y; h.z = (_Float16)v.z; h.w = (_Float16)v.w;
        l.x = (_Float16)(v.x - (float)h.x); l.y = (_Float16)(v.y - (float)h.y);
        l.z = (_Float16)(v.z - (float)h.z); l.w = (_Float16)(v.w - (float)h.w);
        int kdt = kd >> 4, rowin = kd & 15;
        int j0 = jf*4;
        int kk = j0 >> 5, jb = (j0 & 31) >> 3, e0 = j0 & 7;
        int lane = rowin + 16*jb;
        int base = 8192 + ((kdt*2 + kk)*2)*512 + lane*8 + e0;
        *(half4*)(lds + base)       = h;
        *(half4*)(lds + base + 512) = l;
    }
    __syncthreads();

    int w    = t >> 6;
    int lane = t & 63;
    int wbt  = w >> 1;
    int kdh  = w & 1;

    half8 a[2][2];
    #pragma unroll
    for (int kk = 0; kk < 2; kk++)
        #pragma unroll
        for (int hl = 0; hl < 2; hl++)
            a[kk][hl] = *(half8*)(lds + ((wbt*2 + kk)*2 + hl)*512 + lane*8);

    int brow = (lane >> 4) * 4;
    int bcol = lane & 15;

    #pragma unroll
    for (int kdti = 0; kdti < 8; kdti++){
        int kdt = kdh*8 + kdti;
        const _Float16* wb0 = lds + 8192 + ((kdt*2 + 0)*2)*512 + lane*8;
        const _Float16* wb1 = lds + 8192 + ((kdt*2 + 1)*2)*512 + lane*8;
        half8 bh0 = *(half8*)(wb0);
        half8 bl0 = *(half8*)(wb0 + 512);
        half8 bh1 = *(half8*)(wb1);
        half8 bl1 = *(half8*)(wb1 + 512);
        f32x4 acc = {0.f, 0.f, 0.f, 0.f};
        acc = __builtin_amdgcn_mfma_f32_16x16x32_f16(a[0][0], bh0, acc, 0, 0, 0);
        acc = __builtin_amdgcn_mfma_f32_16x16x32_f16(a[0][0], bl0, acc, 0, 0, 0);
        acc = __builtin_amdgcn_mfma_f32_16x16x32_f16(a[0][1], bh0, acc, 0, 0, 0);
        acc = __builtin_amdgcn_mfma_f32_16x16x32_f16(a[1][0], bh1, acc, 0, 0, 0);
        acc = __builtin_amdgcn_mfma_f32_16x16x32_f16(a[1][0], bl1, acc, 0, 0, 0);
        acc = __builtin_amdgcn_mfma_f32_16x16x32_f16(a[1][1], bh1, acc, 0, 0, 0);
        int kd = kdt*16 + bcol;
        #pragma unroll
        for (int r = 0; r < 4; r++){
            int rl = wbt*16 + brow + r;
            if (rl < rows)
                hat[((size_t)(btile*64 + rl)*SS + s)*256 + kd] = acc[r];
        }
    }
}

// Dynamic routing, 3 iters. Lane map: k = bits 2,3; s-bits = {0,1,4,5}.
// s-butterfly: xor1/xor2 on VALU (DPP quad_perm), xor16 via ds_swizzle,
// xor32 via bpermute. Same lane pairings as the round-8 kernel -> the
// floating-point tree is bit-identical to the known-good version.
__global__ void __launch_bounds__(1024) k_route(const float* __restrict__ eb,
                                                const float* __restrict__ mask_,
                                                const float* __restrict__ ws,
                                                const float* __restrict__ hat,
                                                float* __restrict__ out, int b0){
    int bl = blockIdx.x;
    int b = b0 + bl;
    int t = threadIdx.x;
    int lane = t & 63, wv = t >> 6;
    int k = (lane >> 2) & 3;
    int s_local = (lane & 3) | (((lane >> 4) & 3) << 2);
    int s = wv * 16 + s_local;
    __shared__ float part[16][4][64];
    __shared__ float capl[4][68];
    __shared__ float logits[4];
    __shared__ int kms;

    float hat_r[64];
    const float4* hsrc = (const float4*)(hat + (size_t)bl*65536 + ((size_t)s*4 + k)*64);
    #pragma unroll
    for (int jc = 0; jc < 16; jc++){
        float4 v = hsrc[jc];
        hat_r[4*jc] = v.x; hat_r[4*jc+1] = v.y; hat_r[4*jc+2] = v.z; hat_r[4*jc+3] = v.w;
    }
    float fac = ws[OFF_FAC + (size_t)b*SS + s];
    float mk = mask_[(size_t)b*SS + s];
    float cw = 0.f;
    float capv = 0.f;

    for (int it = 0; it < 3; ++it){
        float sw;
        if (it == 0){
            sw = (mk == 0.f) ? 0.f : 0.25f;
        } else {
            // softmax over k (lane bits 2,3): masks 4, 8
            float m = fmaxf(cw, __shfl_xor(cw, 4)); m = fmaxf(m, __shfl_xor(m, 8));
            float e = expf(cw - m);
            float ssum = e + __shfl_xor(e, 4); ssum += __shfl_xor(ssum, 8);
            sw = (mk == 0.f) ? 0.f : (e / ssum);
        }

        // s-reduction: xor1, xor2 (DPP/VALU), xor16 (swizzle), xor32 (bpermute)
        #pragma unroll
        for (int c = 0; c < 4; c++){
            float tmp[16];
            #pragma unroll
            for (int i = 0; i < 16; i++) tmp[i] = sw * hat_r[c*16 + i];
            #pragma unroll
            for (int i = 0; i < 16; i++) tmp[i] = dpp_add_xor1(tmp[i]);
            #pragma unroll
            for (int i = 0; i < 16; i++) tmp[i] = dpp_add_xor2(tmp[i]);
            #pragma unroll
            for (int i = 0; i < 16; i++) tmp[i] = swz_add_xor16(tmp[i]);
            #pragma unroll
            for (int i = 0; i < 16; i++) tmp[i] += __shfl_xor(tmp[i], 32);
            if ((lane & 0x33) == 0){
                float* dst = &part[wv][lane >> 2][c*16];
                #pragma unroll
                for (int i = 0; i < 4; i++)
                    ((float4*)dst)[i] = make_float4(tmp[4*i], tmp[4*i+1], tmp[4*i+2], tmp[4*i+3]);
            }
        }
        __syncthreads();
        if (t < 256){
            int k2 = t >> 6, d = t & 63;
            float cp = 0.f;
            #pragma unroll
            for (int w2 = 0; w2 < 16; w2++) cp += part[w2][k2][d];
            float q = cp * cp;
            #pragma unroll
            for (int msk = 1; msk < 64; msk <<= 1) q += __shfl_xor(q, msk);
            float sc = q / ((1.f + q) * sqrtf(q + 1e-9f));
            capv = sc * cp;
            capl[k2][d] = capv;
        }
        __syncthreads();
        if (it < 2){
            const float4* cp4 = (const float4*)&capl[k][0];
            float dot = 0.f;
            #pragma unroll
            for (int jc = 0; jc < 16; jc++){
                float4 v = cp4[jc];
                dot += hat_r[4*jc]*v.x + hat_r[4*jc+1]*v.y + hat_r[4*jc+2]*v.z + hat_r[4*jc+3]*v.w;
            }
            cw += dot * fac;
        }
        __syncthreads();
    }

    if (t < 256){
        int k2 = t >> 6, d = t & 63;
        out[(size_t)b*256 + t] = capv;
        float qq = capv * eb[(size_t)b*DD + d];
        #pragma unroll
        for (int msk = 1; msk < 64; msk <<= 1) qq += __shfl_xor(qq, msk);
        if (lane == 0) logits[k2] = qq;
    }
    __syncthreads();
    if (t == 0){
        float best = logits[0]; int km = 0;
        for (int kk = 1; kk < 4; kk++) if (logits[kk] > best){ best = logits[kk]; km = kk; }
        kms = km;
    }
    __syncthreads();
    if (t < 64) out[(size_t)BB*256 + (size_t)b*64 + t] = capl[kms][t];
}

__global__ void k_final(const float* __restrict__ phase, const float* __restrict__ ratio,
                        float* ws, float* __restrict__ out){
    if (threadIdx.x == 0){
        float r2a = 0.f, r2b = 0.f;
        for (int g = 0; g < NG; g++){ r2a += ratio[g]*ratio[g]; r2b += phase[g]*phase[g]; }
        float reg2 = sqrtf(r2a) + sqrtf(r2b) / 100000.0f;
        float reg1 = sqrtf(ws[OFF_SCAL + 4]);
        out[(size_t)BB*256 + (size_t)BB*64] = 0.1f*reg1 + reg2 + 1.0f/reg1 + 0.1f/reg2;
    }
}

extern "C" void kernel_launch(void* const* d_in, const int* in_sizes, int n_in,
                              void* d_out, int out_size, void* d_ws, size_t ws_size,
                              hipStream_t stream){
    const float* Xh = (const float*)d_in[0];
    const float* eb = (const float*)d_in[1];
    const float* tb = (const float*)d_in[2];
    const float* th = (const float*)d_in[3];
    const float* mk = (const float*)d_in[4];
    const float* W1 = (const float*)d_in[5];
    const float* b1 = (const float*)d_in[6];
    const float* W2 = (const float*)d_in[7];
    const float* b2 = (const float*)d_in[8];
    const float* ph = (const float*)d_in[9];
    const float* ta = (const float*)d_in[10];
    const float* ra = (const float*)d_in[11];
    const float* ge = (const float*)d_in[12];
    const float* wb = (const float*)d_in[13];
    float* out = (float*)d_out;
    float* ws  = (float*)d_ws;

    hipLaunchKernelGGL(k_init,   dim3(1),    dim3(64),  0, stream, ws);
    hipLaunchKernelGGL(k_min,    dim3(256),  dim3(256), 0, stream, tb, th, ws);
    hipLaunchKernelGGL(k_tables, dim3((PMAX+TPB-1)/TPB), dim3(128), 0, stream, W1, ws);
    hipLaunchKernelGGL(k_gtb,    dim3(BB),   dim3(128), 0, stream, tb, W1, b1, ws);
    hipLaunchKernelGGL(k_factor, dim3(2*BB), dim3(256), 0, stream, tb, th, W2, b2, ws);
    hipLaunchKernelGGL(k_gate,   dim3(BB),   dim3(256), 0, stream, Xh, th, ph, ta, ra, ge, ws);

    long wfloats  = (long)(ws_size / sizeof(float));
    long hatavail = wfloats - (long)OFF_HAT;
    int CH = (int)(hatavail / 65536);      // batches per chunk
    if (CH > BB) CH = BB;
    if (CH >= 128) CH &= ~127;             // keep 64-row tiles full per chunk
    if (CH < 1)  CH = 1;
    float* hatbuf = ws + OFF_HAT;
    for (int c0 = 0; c0 < BB; c0 += CH){
        int nb = BB - c0; if (nb > CH) nb = CH;
        int nbt = (nb + 63) / 64;
        hipLaunchKernelGGL(k_hat,   dim3(nbt, 256), dim3(512),  0, stream, Xh, wb, hatbuf, c0, nb);
        hipLaunchKernelGGL(k_route, dim3(nb),       dim3(1024), 0, stream, eb, mk, ws, hatbuf, out, c0);
    }
    hipLaunchKernelGGL(k_final, dim3(1), dim3(64), 0, stream, ph, ra, ws, out);
}